// Round 10
// baseline (178.031 us; speedup 1.0000x reference)
//
#include <hip/hip_runtime.h>
#include <hip/hip_bf16.h>

// B=2, T=2048, C=1024, H=16, D=64, WINDOW=512. fp32 in/out, bf16 MFMA inside.
// prep -> gemm_qkv (BK=32 m97; K stored pre-scaled by 1/8; V transposed)
// -> attn (S^T form, 32 q/wave, XCD-local grid: x=bh so id%8=bh%8 pins each
// (b,h)'s K/V slice to one XCD's L2) -> gemm_proj (128x64, BK=64).

typedef __bf16 bf16x8 __attribute__((ext_vector_type(8)));
typedef float f32x4 __attribute__((ext_vector_type(4)));

__device__ __forceinline__ unsigned short f2b(float f) {
  unsigned int u = __float_as_uint(f);
  unsigned int r = (u + 0x7FFFu + ((u >> 16) & 1u)) >> 16;
  return (unsigned short)r;
}
__device__ __forceinline__ void async16(const unsigned short* g,
                                        unsigned short* l) {
  __builtin_amdgcn_global_load_lds(
      (const __attribute__((address_space(1))) unsigned int*)g,
      (__attribute__((address_space(3))) unsigned int*)l, 16, 0, 0);
}

// -------- prep: z=0 cvt x -> xb; z=1/2 transpose+cvt w_attn/w_proj ---------
__global__ __launch_bounds__(256) void prep(
    const float* __restrict__ x, const float* __restrict__ w_attn,
    const float* __restrict__ w_proj, unsigned short* __restrict__ xb,
    unsigned short* __restrict__ wT, unsigned short* __restrict__ pT) {
  __shared__ unsigned short tile[32][33];
  const int z = blockIdx.z;
  if (z == 0) {
    const int id = blockIdx.y * 96 + blockIdx.x;
    if (id >= 2048) return;
    const int i = id * 256 + threadIdx.x;
    const float4 a = ((const float4*)x)[i * 2];
    const float4 b = ((const float4*)x)[i * 2 + 1];
    union { unsigned short us[8]; uint4 v; } t;
    t.us[0] = f2b(a.x); t.us[1] = f2b(a.y); t.us[2] = f2b(a.z); t.us[3] = f2b(a.w);
    t.us[4] = f2b(b.x); t.us[5] = f2b(b.y); t.us[6] = f2b(b.z); t.us[7] = f2b(b.w);
    ((uint4*)xb)[i] = t.v;
    return;
  }
  const float* in = (z == 1) ? w_attn : w_proj;
  unsigned short* out = (z == 1) ? wT : pT;
  const int R = 1024, Cc = (z == 1) ? 3072 : 1024;
  if (blockIdx.x * 32 >= Cc) return;
  const int t = threadIdx.x;
  const int tx = t & 31, ty0 = t >> 5;
  const int c0 = blockIdx.x * 32, r0 = blockIdx.y * 32;
  #pragma unroll
  for (int rr = 0; rr < 32; rr += 8)
    tile[ty0 + rr][tx] = f2b(in[(size_t)(r0 + ty0 + rr) * Cc + c0 + tx]);
  __syncthreads();
  #pragma unroll
  for (int rr = 0; rr < 32; rr += 8)
    out[(size_t)(c0 + ty0 + rr) * R + r0 + tx] = tile[tx][ty0 + rr];
}

// -------- qkv GEMM: BK=32 m97 structure (R5/R7/R9-verified) ----------------
// Epilogue: Q natural; K natural pre-scaled by 0.125 (exact in bf16);
// V transposed [(b*16+h)*64+d][t].
__global__ __launch_bounds__(256) void gemm_qkv(
    const unsigned short* __restrict__ A, const unsigned short* __restrict__ Bt,
    unsigned short* __restrict__ qkb, unsigned short* __restrict__ vtb) {
  const int K = 1024;
  __shared__ unsigned short As[128 * 32];
  __shared__ unsigned short Bs[128 * 32];
  const int tid = threadIdx.x;
  const int w = tid >> 6, lane = tid & 63;
  const int quad = lane >> 4, c16 = lane & 15;
  const int m0 = blockIdx.y * 128, n0 = blockIdx.x * 128;
  const int wm = (w & 1) * 64, wn = (w >> 1) * 64;
  const int srow = w * 16 + (lane >> 2);
  const int scol = (lane & 3) * 8;
  const unsigned short* ag0 = A + (size_t)(m0 + srow) * K + scol;
  const unsigned short* ag1 = A + (size_t)(m0 + 64 + srow) * K + scol;
  const unsigned short* bg0 = Bt + (size_t)(n0 + srow) * K + scol;
  const unsigned short* bg1 = Bt + (size_t)(n0 + 64 + srow) * K + scol;
  f32x4 acc[4][4] = {};
  for (int k0 = 0; k0 < K; k0 += 32) {
    async16(ag0 + k0, &As[w * 512]);
    async16(ag1 + k0, &As[w * 512 + 2048]);
    async16(bg0 + k0, &Bs[w * 512]);
    async16(bg1 + k0, &Bs[w * 512 + 2048]);
    __syncthreads();
    bf16x8 af[4], bfr[4];
    #pragma unroll
    for (int mi = 0; mi < 4; ++mi)
      af[mi] = *(const bf16x8*)&As[(wm + mi * 16 + c16) * 32 + quad * 8];
    #pragma unroll
    for (int ni = 0; ni < 4; ++ni)
      bfr[ni] = *(const bf16x8*)&Bs[(wn + ni * 16 + c16) * 32 + quad * 8];
    #pragma unroll
    for (int mi = 0; mi < 4; ++mi)
      #pragma unroll
      for (int ni = 0; ni < 4; ++ni)
        acc[mi][ni] = __builtin_amdgcn_mfma_f32_16x16x32_bf16(
            af[mi], bfr[ni], acc[mi][ni], 0, 0, 0);
    __syncthreads();
  }
  #pragma unroll
  for (int mi = 0; mi < 4; ++mi) {
    const int rbase = m0 + wm + mi * 16 + quad * 4;
    const int bidx = rbase >> 11;
    const int t0 = rbase & 2047;
    #pragma unroll
    for (int ni = 0; ni < 4; ++ni) {
      const int colC = n0 + wn + ni * 16 + c16;
      if (colC < 2048) {
        const float kscale = (colC >= 1024) ? 0.125f : 1.0f;  // K pre-scaled
        #pragma unroll
        for (int r = 0; r < 4; ++r)
          qkb[(size_t)(rbase + r) * 2048 + colC] = f2b(acc[mi][ni][r] * kscale);
      } else {
        const int d = colC - 2048;
        const int hh = d >> 6, dd = d & 63;
        ushort4 pk;
        pk.x = f2b(acc[mi][ni][0]); pk.y = f2b(acc[mi][ni][1]);
        pk.z = f2b(acc[mi][ni][2]); pk.w = f2b(acc[mi][ni][3]);
        *(ushort4*)(vtb + (size_t)((bidx * 16 + hh) * 64 + dd) * 2048 + t0) = pk;
      }
    }
  }
}

// -------- proj GEMM: 128x64 tiles, BK=64, XOR swizzle (R8/R9 form) ---------
__global__ __launch_bounds__(256) void gemm_proj(
    const unsigned short* __restrict__ A, const unsigned short* __restrict__ Bt,
    float* __restrict__ C, int M, int N, int K) {
  __shared__ unsigned short As[128 * 64];
  __shared__ unsigned short Bs[64 * 64];
  const int tid = threadIdx.x;
  const int w = tid >> 6, lane = tid & 63;
  const int quad = lane >> 4, c16 = lane & 15;
  const int c7 = c16 & 7;
  const int m0 = blockIdx.y * 128, n0 = blockIdx.x * 64;
  const int wm = (w & 1) * 64, wn = (w >> 1) * 32;
  const int lrow = lane >> 3;
  const int cg = (lane & 7) ^ lrow;
  const unsigned short* ag = A + (size_t)(m0 + w * 32 + lrow) * K + cg * 8;
  const unsigned short* bg = Bt + (size_t)(n0 + w * 16 + lrow) * K + cg * 8;
  f32x4 acc[4][2] = {};
  for (int k0 = 0; k0 < K; k0 += 64) {
    #pragma unroll
    for (int rnd = 0; rnd < 4; ++rnd)
      async16(ag + (size_t)rnd * 8 * K + k0, &As[(w * 32 + rnd * 8) * 64]);
    #pragma unroll
    for (int rnd = 0; rnd < 2; ++rnd)
      async16(bg + (size_t)rnd * 8 * K + k0, &Bs[(w * 16 + rnd * 8) * 64]);
    __syncthreads();
    #pragma unroll
    for (int ks = 0; ks < 2; ++ks) {
      const int gsw = ((ks * 4 + quad) ^ c7) * 8;
      bf16x8 af[4], bfr[2];
      #pragma unroll
      for (int mi = 0; mi < 4; ++mi)
        af[mi] = *(const bf16x8*)&As[(wm + mi * 16 + c16) * 64 + gsw];
      #pragma unroll
      for (int ni = 0; ni < 2; ++ni)
        bfr[ni] = *(const bf16x8*)&Bs[(wn + ni * 16 + c16) * 64 + gsw];
      #pragma unroll
      for (int mi = 0; mi < 4; ++mi)
        #pragma unroll
        for (int ni = 0; ni < 2; ++ni)
          acc[mi][ni] = __builtin_amdgcn_mfma_f32_16x16x32_bf16(
              af[mi], bfr[ni], acc[mi][ni], 0, 0, 0);
    }
    __syncthreads();
  }
  #pragma unroll
  for (int mi = 0; mi < 4; ++mi)
    #pragma unroll
    for (int ni = 0; ni < 2; ++ni) {
      const int colC = n0 + wn + ni * 16 + c16;
      const int rbase = m0 + wm + mi * 16 + quad * 4;
      #pragma unroll
      for (int r = 0; r < 4; ++r)
        C[(size_t)(rbase + r) * N + colC] = acc[mi][ni][r];
    }
}

// -------- flash attention, S^T form, 32 q/wave, XCD-local grid -------------
// grid = (x=bh 32, y=qtile 16): linear id % 8 = bh % 8 -> each XCD owns 4
// (b,h) slices; K/V/Q working set ~3MB fits its 4MB L2 (was qtile-pinned:
// 16MB set -> thrash, 68MB FETCH). K arrives pre-scaled by 1/8.
__global__ __launch_bounds__(256) void attn_flash(
    const unsigned short* __restrict__ qk,   // [4096][2048]
    const unsigned short* __restrict__ vtg,  // [(b*16+h)*64+d][2048]
    unsigned short* __restrict__ y) {        // [4096][1024]
  __shared__ unsigned short Ks[2][64 * 64];
  __shared__ unsigned short Vs[2][64 * 64];
  __shared__ unsigned short Pt[128 * 72];    // [q][key]
  const int tid = threadIdx.x;
  const int w = tid >> 6, lane = tid & 63;
  const int quad = lane >> 4, c16 = lane & 15;
  const int c7 = c16 & 7;
  const int b = blockIdx.x >> 4, h = blockIdx.x & 15;   // x = bh
  const int i0 = blockIdx.y * 128;                      // y = qtile
  const int q0 = i0 + w * 32;

  bf16x8 qb[2][2];
  {
    const size_t qr0 = (size_t)(b * 2048 + q0 + c16) * 2048 + h * 64;
    const size_t qr1 = (size_t)(b * 2048 + q0 + 16 + c16) * 2048 + h * 64;
    qb[0][0] = *(const bf16x8*)(qk + qr0 + quad * 8);
    qb[0][1] = *(const bf16x8*)(qk + qr0 + 32 + quad * 8);
    qb[1][0] = *(const bf16x8*)(qk + qr1 + quad * 8);
    qb[1][1] = *(const bf16x8*)(qk + qr1 + 32 + quad * 8);
  }

  const int lrow = lane >> 3;
  const int cg = (lane & 7) ^ lrow;
  const int row0 = w * 16 + lrow;
  const int t_start = (i0 >= 512) ? ((i0 - 511) >> 6) : 0;
  const int t_end = (i0 + 127) >> 6;

  const unsigned short* kp0 =
      qk + (size_t)(b * 2048 + t_start * 64 + row0) * 2048 + 1024 + h * 64 + cg * 8;
  const unsigned short* kp1 = kp0 + (size_t)8 * 2048;
  const unsigned short* vp0 =
      vtg + (size_t)((b * 16 + h) * 64 + row0) * 2048 + t_start * 64 + cg * 8;
  const unsigned short* vp1 = vp0 + (size_t)8 * 2048;

  async16(kp0, &Ks[0][(w * 16) * 64]);
  async16(kp1, &Ks[0][(w * 16 + 8) * 64]);
  async16(vp0, &Vs[0][(w * 16) * 64]);
  async16(vp1, &Vs[0][(w * 16 + 8) * 64]);
  kp0 += 131072; kp1 += 131072; vp0 += 64; vp1 += 64;
  __syncthreads();

  f32x4 o[4][2] = {};
  float lsum[2] = {0.f, 0.f};
  int cur = 0;

  for (int t = t_start; t <= t_end; ++t) {
    if (t < t_end) {
      unsigned short* kb = &Ks[cur ^ 1][0];
      unsigned short* vb = &Vs[cur ^ 1][0];
      async16(kp0, kb + (w * 16) * 64);
      async16(kp1, kb + (w * 16 + 8) * 64);
      async16(vp0, vb + (w * 16) * 64);
      async16(vp1, vb + (w * 16 + 8) * 64);
      kp0 += 131072; kp1 += 131072; vp0 += 64; vp1 += 64;
    }
    const int kbase = t * 64;
    if (kbase <= q0 + 31 && kbase + 63 >= q0 - 511) {
      const unsigned short* Kc = &Ks[cur][0];
      const unsigned short* Vc = &Vs[cur][0];

      f32x4 s[4][2] = {};
      #pragma unroll
      for (int nb = 0; nb < 4; ++nb) {
        const int row = nb * 16 + c16;
        bf16x8 a0 = *(const bf16x8*)&Kc[row * 64 + (quad ^ c7) * 8];
        bf16x8 a1 = *(const bf16x8*)&Kc[row * 64 + ((quad + 4) ^ c7) * 8];
        #pragma unroll
        for (int n2 = 0; n2 < 2; ++n2) {
          s[nb][n2] = __builtin_amdgcn_mfma_f32_16x16x32_bf16(
              a0, qb[n2][0], s[nb][n2], 0, 0, 0);
          s[nb][n2] = __builtin_amdgcn_mfma_f32_16x16x32_bf16(
              a1, qb[n2][1], s[nb][n2], 0, 0, 0);
        }
      }

      const bool full = (kbase + 63 <= q0) && (kbase >= q0 - 480);
      #pragma unroll
      for (int n2 = 0; n2 < 2; ++n2) {
        const int iq = q0 + n2 * 16 + c16;
        #pragma unroll
        for (int nb = 0; nb < 4; ++nb) {
          ushort4 pk;
          unsigned short* pks = (unsigned short*)&pk;
          #pragma unroll
          for (int r = 0; r < 4; ++r) {
            float sv = s[nb][n2][r];          // K pre-scaled: no mul here
            if (!full) {
              const int j = kbase + nb * 16 + quad * 4 + r;
              const bool valid = (j <= iq) && (j >= iq - 511);
              sv = valid ? sv : -3.0e38f;
            }
            const unsigned int pu = __float_as_uint(__expf(sv)) & 0xffff0000u;
            lsum[n2] += __uint_as_float(pu);
            pks[r] = (unsigned short)(pu >> 16);
          }
          *(ushort4*)&Pt[(w * 32 + n2 * 16 + c16) * 72 + nb * 16 + quad * 4] = pk;
        }
      }

      #pragma unroll
      for (int ks2 = 0; ks2 < 2; ++ks2) {
        bf16x8 pb0 = *(const bf16x8*)&Pt[(w * 32 + c16) * 72 + ks2 * 32 + quad * 8];
        bf16x8 pb1 = *(const bf16x8*)&Pt[(w * 32 + 16 + c16) * 72 + ks2 * 32 + quad * 8];
        #pragma unroll
        for (int nb = 0; nb < 4; ++nb) {
          const int row = nb * 16 + c16;
          bf16x8 va = *(const bf16x8*)&Vc[row * 64 + ((quad + 4 * ks2) ^ c7) * 8];
          o[nb][0] = __builtin_amdgcn_mfma_f32_16x16x32_bf16(va, pb0, o[nb][0], 0, 0, 0);
          o[nb][1] = __builtin_amdgcn_mfma_f32_16x16x32_bf16(va, pb1, o[nb][1], 0, 0, 0);
        }
      }
    }
    __syncthreads();
    cur ^= 1;
  }

  #pragma unroll
  for (int n2 = 0; n2 < 2; ++n2) {
    float rs = lsum[n2];
    rs += __shfl_xor(rs, 16);
    rs += __shfl_xor(rs, 32);
    const float inv = 1.0f / rs;
    const int iq = q0 + n2 * 16 + c16;
    #pragma unroll
    for (int nb = 0; nb < 4; ++nb) {
      ushort4 pk;
      unsigned short* pks = (unsigned short*)&pk;
      #pragma unroll
      for (int r = 0; r < 4; ++r) pks[r] = f2b(o[nb][n2][r] * inv);
      *(ushort4*)(y + (size_t)(b * 2048 + iq) * 1024 + h * 64 + nb * 16 + quad * 4) = pk;
    }
  }
}

// ---------------------------------------------------------------------------
extern "C" void kernel_launch(void* const* d_in, const int* in_sizes, int n_in,
                              void* d_out, int out_size, void* d_ws, size_t ws_size,
                              hipStream_t stream) {
  const float* x      = (const float*)d_in[0];  // [4096,1024] fp32
  const float* w_attn = (const float*)d_in[1];  // [1024,3072] fp32
  const float* w_proj = (const float*)d_in[2];  // [1024,1024] fp32
  float* out = (float*)d_out;                   // [4096,1024] fp32

  // ws (bf16 elems): qkb 8M | vtb 4M | wT 3M | pT 1M | xb/y 4M  = 40MB
  unsigned short* qkb = (unsigned short*)d_ws;        // [4096][2048]
  unsigned short* vtb = qkb + (size_t)4096 * 2048;    // [2048][2048]
  unsigned short* wT  = vtb + (size_t)2048 * 2048;    // [3072][1024]
  unsigned short* pT  = wT + (size_t)3072 * 1024;     // [1024][1024]
  unsigned short* xb  = pT + (size_t)1024 * 1024;     // [4096][1024]
  unsigned short* y   = xb;                           // reuse (xb dead post-GEMM1)

  prep<<<dim3(96, 32, 3), 256, 0, stream>>>(x, w_attn, w_proj, xb, wT, pT);

  gemm_qkv<<<dim3(3072 / 128, 4096 / 128), 256, 0, stream>>>(xb, wT, qkb, vtb);

  attn_flash<<<dim3(32, 16), 256, 0, stream>>>(qkb, vtb, y);

  gemm_proj<<<dim3(1024 / 64, 4096 / 128), 256, 0, stream>>>(
      y, pT, out, 4096, 1024, 1024);
}

// Round 11
// 162.869 us; speedup vs baseline: 1.0931x; 1.0931x over previous
//
#include <hip/hip_runtime.h>
#include <hip/hip_bf16.h>

// B=2, T=2048, C=1024, H=16, D=64, WINDOW=512. fp32 in/out, bf16 MFMA inside.
// R9 state + XOR-4 LDS group swizzle in gemm_qkv (kills half the 8-way
// frag-read bank conflicts; no other changes). prep -> gemm_qkv (BK=32 m97)
// -> attn (S^T form, 32 q/wave, grid x=qtile) -> gemm_proj (128x64, BK=64).

typedef __bf16 bf16x8 __attribute__((ext_vector_type(8)));
typedef float f32x4 __attribute__((ext_vector_type(4)));

__device__ __forceinline__ unsigned short f2b(float f) {
  unsigned int u = __float_as_uint(f);
  unsigned int r = (u + 0x7FFFu + ((u >> 16) & 1u)) >> 16;
  return (unsigned short)r;
}
__device__ __forceinline__ void async16(const unsigned short* g,
                                        unsigned short* l) {
  __builtin_amdgcn_global_load_lds(
      (const __attribute__((address_space(1))) unsigned int*)g,
      (__attribute__((address_space(3))) unsigned int*)l, 16, 0, 0);
}

// -------- prep: z=0 cvt x -> xb; z=1/2 transpose+cvt w_attn/w_proj ---------
__global__ __launch_bounds__(256) void prep(
    const float* __restrict__ x, const float* __restrict__ w_attn,
    const float* __restrict__ w_proj, unsigned short* __restrict__ xb,
    unsigned short* __restrict__ wT, unsigned short* __restrict__ pT) {
  __shared__ unsigned short tile[32][33];
  const int z = blockIdx.z;
  if (z == 0) {
    const int id = blockIdx.y * 96 + blockIdx.x;
    if (id >= 2048) return;
    const int i = id * 256 + threadIdx.x;
    const float4 a = ((const float4*)x)[i * 2];
    const float4 b = ((const float4*)x)[i * 2 + 1];
    union { unsigned short us[8]; uint4 v; } t;
    t.us[0] = f2b(a.x); t.us[1] = f2b(a.y); t.us[2] = f2b(a.z); t.us[3] = f2b(a.w);
    t.us[4] = f2b(b.x); t.us[5] = f2b(b.y); t.us[6] = f2b(b.z); t.us[7] = f2b(b.w);
    ((uint4*)xb)[i] = t.v;
    return;
  }
  const float* in = (z == 1) ? w_attn : w_proj;
  unsigned short* out = (z == 1) ? wT : pT;
  const int R = 1024, Cc = (z == 1) ? 3072 : 1024;
  if (blockIdx.x * 32 >= Cc) return;
  const int t = threadIdx.x;
  const int tx = t & 31, ty0 = t >> 5;
  const int c0 = blockIdx.x * 32, r0 = blockIdx.y * 32;
  #pragma unroll
  for (int rr = 0; rr < 32; rr += 8)
    tile[ty0 + rr][tx] = f2b(in[(size_t)(r0 + ty0 + rr) * Cc + c0 + tx]);
  __syncthreads();
  #pragma unroll
  for (int rr = 0; rr < 32; rr += 8)
    out[(size_t)(c0 + ty0 + rr) * R + r0 + tx] = tile[tx][ty0 + rr];
}

// -------- qkv GEMM: BK=32 m97 structure + XOR-4 group swizzle --------------
// LDS group g (8 elems) of row r holds source col-group g^(r&3): staging
// lane L fetches source group (L&3)^((L>>2)&3) (64B/4-lane coalescing kept);
// frag read uses group quad^(c16&3). Epilogue identical to R9.
__global__ __launch_bounds__(256) void gemm_qkv(
    const unsigned short* __restrict__ A, const unsigned short* __restrict__ Bt,
    unsigned short* __restrict__ qkb, unsigned short* __restrict__ vtb) {
  const int K = 1024;
  __shared__ unsigned short As[128 * 32];
  __shared__ unsigned short Bs[128 * 32];
  const int tid = threadIdx.x;
  const int w = tid >> 6, lane = tid & 63;
  const int quad = lane >> 4, c16 = lane & 15;
  const int m0 = blockIdx.y * 128, n0 = blockIdx.x * 128;
  const int wm = (w & 1) * 64, wn = (w >> 1) * 64;
  const int srow = w * 16 + (lane >> 2);
  const int scol = ((lane & 3) ^ ((lane >> 2) & 3)) * 8;  // XOR-4 swizzle
  const unsigned short* ag0 = A + (size_t)(m0 + srow) * K + scol;
  const unsigned short* ag1 = A + (size_t)(m0 + 64 + srow) * K + scol;
  const unsigned short* bg0 = Bt + (size_t)(n0 + srow) * K + scol;
  const unsigned short* bg1 = Bt + (size_t)(n0 + 64 + srow) * K + scol;
  const int gsw = (quad ^ (c16 & 3)) * 8;                 // frag-read group
  f32x4 acc[4][4] = {};
  for (int k0 = 0; k0 < K; k0 += 32) {
    async16(ag0 + k0, &As[w * 512]);
    async16(ag1 + k0, &As[w * 512 + 2048]);
    async16(bg0 + k0, &Bs[w * 512]);
    async16(bg1 + k0, &Bs[w * 512 + 2048]);
    __syncthreads();
    bf16x8 af[4], bfr[4];
    #pragma unroll
    for (int mi = 0; mi < 4; ++mi)
      af[mi] = *(const bf16x8*)&As[(wm + mi * 16 + c16) * 32 + gsw];
    #pragma unroll
    for (int ni = 0; ni < 4; ++ni)
      bfr[ni] = *(const bf16x8*)&Bs[(wn + ni * 16 + c16) * 32 + gsw];
    #pragma unroll
    for (int mi = 0; mi < 4; ++mi)
      #pragma unroll
      for (int ni = 0; ni < 4; ++ni)
        acc[mi][ni] = __builtin_amdgcn_mfma_f32_16x16x32_bf16(
            af[mi], bfr[ni], acc[mi][ni], 0, 0, 0);
    __syncthreads();
  }
  #pragma unroll
  for (int mi = 0; mi < 4; ++mi) {
    const int rbase = m0 + wm + mi * 16 + quad * 4;
    const int bidx = rbase >> 11;
    const int t0 = rbase & 2047;
    #pragma unroll
    for (int ni = 0; ni < 4; ++ni) {
      const int colC = n0 + wn + ni * 16 + c16;
      if (colC < 2048) {
        #pragma unroll
        for (int r = 0; r < 4; ++r)
          qkb[(size_t)(rbase + r) * 2048 + colC] = f2b(acc[mi][ni][r]);
      } else {
        const int d = colC - 2048;
        const int hh = d >> 6, dd = d & 63;
        ushort4 pk;
        pk.x = f2b(acc[mi][ni][0]); pk.y = f2b(acc[mi][ni][1]);
        pk.z = f2b(acc[mi][ni][2]); pk.w = f2b(acc[mi][ni][3]);
        *(ushort4*)(vtb + (size_t)((bidx * 16 + hh) * 64 + dd) * 2048 + t0) = pk;
      }
    }
  }
}

// -------- proj GEMM: 128x64 tiles, BK=64, XOR swizzle (R8/R9 form) ---------
__global__ __launch_bounds__(256) void gemm_proj(
    const unsigned short* __restrict__ A, const unsigned short* __restrict__ Bt,
    float* __restrict__ C, int M, int N, int K) {
  __shared__ unsigned short As[128 * 64];
  __shared__ unsigned short Bs[64 * 64];
  const int tid = threadIdx.x;
  const int w = tid >> 6, lane = tid & 63;
  const int quad = lane >> 4, c16 = lane & 15;
  const int c7 = c16 & 7;
  const int m0 = blockIdx.y * 128, n0 = blockIdx.x * 64;
  const int wm = (w & 1) * 64, wn = (w >> 1) * 32;
  const int lrow = lane >> 3;
  const int cg = (lane & 7) ^ lrow;
  const unsigned short* ag = A + (size_t)(m0 + w * 32 + lrow) * K + cg * 8;
  const unsigned short* bg = Bt + (size_t)(n0 + w * 16 + lrow) * K + cg * 8;
  f32x4 acc[4][2] = {};
  for (int k0 = 0; k0 < K; k0 += 64) {
    #pragma unroll
    for (int rnd = 0; rnd < 4; ++rnd)
      async16(ag + (size_t)rnd * 8 * K + k0, &As[(w * 32 + rnd * 8) * 64]);
    #pragma unroll
    for (int rnd = 0; rnd < 2; ++rnd)
      async16(bg + (size_t)rnd * 8 * K + k0, &Bs[(w * 16 + rnd * 8) * 64]);
    __syncthreads();
    #pragma unroll
    for (int ks = 0; ks < 2; ++ks) {
      const int gsw = ((ks * 4 + quad) ^ c7) * 8;
      bf16x8 af[4], bfr[2];
      #pragma unroll
      for (int mi = 0; mi < 4; ++mi)
        af[mi] = *(const bf16x8*)&As[(wm + mi * 16 + c16) * 64 + gsw];
      #pragma unroll
      for (int ni = 0; ni < 2; ++ni)
        bfr[ni] = *(const bf16x8*)&Bs[(wn + ni * 16 + c16) * 64 + gsw];
      #pragma unroll
      for (int mi = 0; mi < 4; ++mi)
        #pragma unroll
        for (int ni = 0; ni < 2; ++ni)
          acc[mi][ni] = __builtin_amdgcn_mfma_f32_16x16x32_bf16(
              af[mi], bfr[ni], acc[mi][ni], 0, 0, 0);
    }
    __syncthreads();
  }
  #pragma unroll
  for (int mi = 0; mi < 4; ++mi)
    #pragma unroll
    for (int ni = 0; ni < 2; ++ni) {
      const int colC = n0 + wn + ni * 16 + c16;
      const int rbase = m0 + wm + mi * 16 + quad * 4;
      #pragma unroll
      for (int r = 0; r < 4; ++r)
        C[(size_t)(rbase + r) * N + colC] = acc[mi][ni][r];
    }
}

// -------- flash attention, S^T form, 32 q/wave (R7/R9-verified) ------------
__global__ __launch_bounds__(256) void attn_flash(
    const unsigned short* __restrict__ qk,   // [4096][2048]
    const unsigned short* __restrict__ vtg,  // [(b*16+h)*64+d][2048]
    unsigned short* __restrict__ y) {        // [4096][1024]
  __shared__ unsigned short Ks[2][64 * 64];
  __shared__ unsigned short Vs[2][64 * 64];
  __shared__ unsigned short Pt[128 * 72];    // [q][key]
  const int tid = threadIdx.x;
  const int w = tid >> 6, lane = tid & 63;
  const int quad = lane >> 4, c16 = lane & 15;
  const int c7 = c16 & 7;
  const int b = blockIdx.y >> 4, h = blockIdx.y & 15;
  const int i0 = blockIdx.x * 128;
  const int q0 = i0 + w * 32;

  bf16x8 qb[2][2];
  {
    const size_t qr0 = (size_t)(b * 2048 + q0 + c16) * 2048 + h * 64;
    const size_t qr1 = (size_t)(b * 2048 + q0 + 16 + c16) * 2048 + h * 64;
    qb[0][0] = *(const bf16x8*)(qk + qr0 + quad * 8);
    qb[0][1] = *(const bf16x8*)(qk + qr0 + 32 + quad * 8);
    qb[1][0] = *(const bf16x8*)(qk + qr1 + quad * 8);
    qb[1][1] = *(const bf16x8*)(qk + qr1 + 32 + quad * 8);
  }

  const int lrow = lane >> 3;
  const int cg = (lane & 7) ^ lrow;
  const int row0 = w * 16 + lrow;
  const int t_start = (i0 >= 512) ? ((i0 - 511) >> 6) : 0;
  const int t_end = (i0 + 127) >> 6;

  const unsigned short* kp0 =
      qk + (size_t)(b * 2048 + t_start * 64 + row0) * 2048 + 1024 + h * 64 + cg * 8;
  const unsigned short* kp1 = kp0 + (size_t)8 * 2048;
  const unsigned short* vp0 =
      vtg + (size_t)((b * 16 + h) * 64 + row0) * 2048 + t_start * 64 + cg * 8;
  const unsigned short* vp1 = vp0 + (size_t)8 * 2048;

  async16(kp0, &Ks[0][(w * 16) * 64]);
  async16(kp1, &Ks[0][(w * 16 + 8) * 64]);
  async16(vp0, &Vs[0][(w * 16) * 64]);
  async16(vp1, &Vs[0][(w * 16 + 8) * 64]);
  kp0 += 131072; kp1 += 131072; vp0 += 64; vp1 += 64;
  __syncthreads();

  f32x4 o[4][2] = {};
  float lsum[2] = {0.f, 0.f};
  int cur = 0;

  for (int t = t_start; t <= t_end; ++t) {
    if (t < t_end) {
      unsigned short* kb = &Ks[cur ^ 1][0];
      unsigned short* vb = &Vs[cur ^ 1][0];
      async16(kp0, kb + (w * 16) * 64);
      async16(kp1, kb + (w * 16 + 8) * 64);
      async16(vp0, vb + (w * 16) * 64);
      async16(vp1, vb + (w * 16 + 8) * 64);
      kp0 += 131072; kp1 += 131072; vp0 += 64; vp1 += 64;
    }
    const int kbase = t * 64;
    if (kbase <= q0 + 31 && kbase + 63 >= q0 - 511) {
      const unsigned short* Kc = &Ks[cur][0];
      const unsigned short* Vc = &Vs[cur][0];

      f32x4 s[4][2] = {};
      #pragma unroll
      for (int nb = 0; nb < 4; ++nb) {
        const int row = nb * 16 + c16;
        bf16x8 a0 = *(const bf16x8*)&Kc[row * 64 + (quad ^ c7) * 8];
        bf16x8 a1 = *(const bf16x8*)&Kc[row * 64 + ((quad + 4) ^ c7) * 8];
        #pragma unroll
        for (int n2 = 0; n2 < 2; ++n2) {
          s[nb][n2] = __builtin_amdgcn_mfma_f32_16x16x32_bf16(
              a0, qb[n2][0], s[nb][n2], 0, 0, 0);
          s[nb][n2] = __builtin_amdgcn_mfma_f32_16x16x32_bf16(
              a1, qb[n2][1], s[nb][n2], 0, 0, 0);
        }
      }

      const bool full = (kbase + 63 <= q0) && (kbase >= q0 - 480);
      #pragma unroll
      for (int n2 = 0; n2 < 2; ++n2) {
        const int iq = q0 + n2 * 16 + c16;
        #pragma unroll
        for (int nb = 0; nb < 4; ++nb) {
          ushort4 pk;
          unsigned short* pks = (unsigned short*)&pk;
          #pragma unroll
          for (int r = 0; r < 4; ++r) {
            float sv = s[nb][n2][r] * 0.125f;
            if (!full) {
              const int j = kbase + nb * 16 + quad * 4 + r;
              const bool valid = (j <= iq) && (j >= iq - 511);
              sv = valid ? sv : -3.0e38f;
            }
            const unsigned int pu = __float_as_uint(__expf(sv)) & 0xffff0000u;
            lsum[n2] += __uint_as_float(pu);
            pks[r] = (unsigned short)(pu >> 16);
          }
          *(ushort4*)&Pt[(w * 32 + n2 * 16 + c16) * 72 + nb * 16 + quad * 4] = pk;
        }
      }

      #pragma unroll
      for (int ks2 = 0; ks2 < 2; ++ks2) {
        bf16x8 pb0 = *(const bf16x8*)&Pt[(w * 32 + c16) * 72 + ks2 * 32 + quad * 8];
        bf16x8 pb1 = *(const bf16x8*)&Pt[(w * 32 + 16 + c16) * 72 + ks2 * 32 + quad * 8];
        #pragma unroll
        for (int nb = 0; nb < 4; ++nb) {
          const int row = nb * 16 + c16;
          bf16x8 va = *(const bf16x8*)&Vc[row * 64 + ((quad + 4 * ks2) ^ c7) * 8];
          o[nb][0] = __builtin_amdgcn_mfma_f32_16x16x32_bf16(va, pb0, o[nb][0], 0, 0, 0);
          o[nb][1] = __builtin_amdgcn_mfma_f32_16x16x32_bf16(va, pb1, o[nb][1], 0, 0, 0);
        }
      }
    }
    __syncthreads();
    cur ^= 1;
  }

  #pragma unroll
  for (int n2 = 0; n2 < 2; ++n2) {
    float rs = lsum[n2];
    rs += __shfl_xor(rs, 16);
    rs += __shfl_xor(rs, 32);
    const float inv = 1.0f / rs;
    const int iq = q0 + n2 * 16 + c16;
    #pragma unroll
    for (int nb = 0; nb < 4; ++nb) {
      ushort4 pk;
      unsigned short* pks = (unsigned short*)&pk;
      #pragma unroll
      for (int r = 0; r < 4; ++r) pks[r] = f2b(o[nb][n2][r] * inv);
      *(ushort4*)(y + (size_t)(b * 2048 + iq) * 1024 + h * 64 + nb * 16 + quad * 4) = pk;
    }
  }
}

// ---------------------------------------------------------------------------
extern "C" void kernel_launch(void* const* d_in, const int* in_sizes, int n_in,
                              void* d_out, int out_size, void* d_ws, size_t ws_size,
                              hipStream_t stream) {
  const float* x      = (const float*)d_in[0];  // [4096,1024] fp32
  const float* w_attn = (const float*)d_in[1];  // [1024,3072] fp32
  const float* w_proj = (const float*)d_in[2];  // [1024,1024] fp32
  float* out = (float*)d_out;                   // [4096,1024] fp32

  // ws (bf16 elems): qkb 8M | vtb 4M | wT 3M | pT 1M | xb/y 4M  = 40MB
  unsigned short* qkb = (unsigned short*)d_ws;        // [4096][2048]
  unsigned short* vtb = qkb + (size_t)4096 * 2048;    // [2048][2048]
  unsigned short* wT  = vtb + (size_t)2048 * 2048;    // [3072][1024]
  unsigned short* pT  = wT + (size_t)3072 * 1024;     // [1024][1024]
  unsigned short* xb  = pT + (size_t)1024 * 1024;     // [4096][1024]
  unsigned short* y   = xb;                           // reuse (xb dead post-GEMM1)

  prep<<<dim3(96, 32, 3), 256, 0, stream>>>(x, w_attn, w_proj, xb, wT, pT);

  gemm_qkv<<<dim3(3072 / 128, 4096 / 128), 256, 0, stream>>>(xb, wT, qkb, vtb);

  attn_flash<<<dim3(16, 32), 256, 0, stream>>>(qkb, vtb, y);

  gemm_proj<<<dim3(1024 / 64, 4096 / 128), 256, 0, stream>>>(
      y, pT, out, 4096, 1024, 1024);
}

// Round 12
// 162.010 us; speedup vs baseline: 1.0989x; 1.0053x over previous
//
#include <hip/hip_runtime.h>
#include <hip/hip_bf16.h>

// B=2, T=2048, C=1024, H=16, D=64, WINDOW=512. fp32 in/out, bf16 MFMA inside.
// R11 state + XCD-rectangle swizzle in gemm_qkv (8 XCD rectangles of
// 8 m-tiles x 12 n-tiles: per-XCD L2 footprint 8.75 -> 5 MB).
// prep -> gemm_qkv (BK=32 m97) -> attn (S^T, 32 q/wave) -> gemm_proj.

typedef __bf16 bf16x8 __attribute__((ext_vector_type(8)));
typedef float f32x4 __attribute__((ext_vector_type(4)));

__device__ __forceinline__ unsigned short f2b(float f) {
  unsigned int u = __float_as_uint(f);
  unsigned int r = (u + 0x7FFFu + ((u >> 16) & 1u)) >> 16;
  return (unsigned short)r;
}
__device__ __forceinline__ void async16(const unsigned short* g,
                                        unsigned short* l) {
  __builtin_amdgcn_global_load_lds(
      (const __attribute__((address_space(1))) unsigned int*)g,
      (__attribute__((address_space(3))) unsigned int*)l, 16, 0, 0);
}

// -------- prep: z=0 cvt x -> xb; z=1/2 transpose+cvt w_attn/w_proj ---------
__global__ __launch_bounds__(256) void prep(
    const float* __restrict__ x, const float* __restrict__ w_attn,
    const float* __restrict__ w_proj, unsigned short* __restrict__ xb,
    unsigned short* __restrict__ wT, unsigned short* __restrict__ pT) {
  __shared__ unsigned short tile[32][33];
  const int z = blockIdx.z;
  if (z == 0) {
    const int id = blockIdx.y * 96 + blockIdx.x;
    if (id >= 2048) return;
    const int i = id * 256 + threadIdx.x;
    const float4 a = ((const float4*)x)[i * 2];
    const float4 b = ((const float4*)x)[i * 2 + 1];
    union { unsigned short us[8]; uint4 v; } t;
    t.us[0] = f2b(a.x); t.us[1] = f2b(a.y); t.us[2] = f2b(a.z); t.us[3] = f2b(a.w);
    t.us[4] = f2b(b.x); t.us[5] = f2b(b.y); t.us[6] = f2b(b.z); t.us[7] = f2b(b.w);
    ((uint4*)xb)[i] = t.v;
    return;
  }
  const float* in = (z == 1) ? w_attn : w_proj;
  unsigned short* out = (z == 1) ? wT : pT;
  const int R = 1024, Cc = (z == 1) ? 3072 : 1024;
  if (blockIdx.x * 32 >= Cc) return;
  const int t = threadIdx.x;
  const int tx = t & 31, ty0 = t >> 5;
  const int c0 = blockIdx.x * 32, r0 = blockIdx.y * 32;
  #pragma unroll
  for (int rr = 0; rr < 32; rr += 8)
    tile[ty0 + rr][tx] = f2b(in[(size_t)(r0 + ty0 + rr) * Cc + c0 + tx]);
  __syncthreads();
  #pragma unroll
  for (int rr = 0; rr < 32; rr += 8)
    out[(size_t)(c0 + ty0 + rr) * R + r0 + tx] = tile[tx][ty0 + rr];
}

// -------- qkv GEMM: BK=32 m97 + XOR-4 swizzle + XCD-rectangle map ----------
// Tile grid 32m x 24n partitioned into 8 rectangles (8m x 12n); XCD id%8
// owns one rectangle -> per-XCD L2 footprint A 2MB + B 3MB = 5MB (was 8.75).
// Uniform block cost -> reorder is tail-safe.
__global__ __launch_bounds__(256) void gemm_qkv(
    const unsigned short* __restrict__ A, const unsigned short* __restrict__ Bt,
    unsigned short* __restrict__ qkb, unsigned short* __restrict__ vtb) {
  const int K = 1024;
  __shared__ unsigned short As[128 * 32];
  __shared__ unsigned short Bs[128 * 32];
  const int tid = threadIdx.x;
  const int w = tid >> 6, lane = tid & 63;
  const int quad = lane >> 4, c16 = lane & 15;
  const int id = blockIdx.x + 24 * blockIdx.y;   // 0..767
  const int xcd = id & 7, j = id >> 3;           // j: 0..95
  const int mt = (xcd & 3) * 8 + (j & 7);        // 0..31
  const int nt = (xcd >> 2) * 12 + (j >> 3);     // 0..23
  const int m0 = mt * 128, n0 = nt * 128;
  const int wm = (w & 1) * 64, wn = (w >> 1) * 64;
  const int srow = w * 16 + (lane >> 2);
  const int scol = ((lane & 3) ^ ((lane >> 2) & 3)) * 8;  // XOR-4 swizzle
  const unsigned short* ag0 = A + (size_t)(m0 + srow) * K + scol;
  const unsigned short* ag1 = A + (size_t)(m0 + 64 + srow) * K + scol;
  const unsigned short* bg0 = Bt + (size_t)(n0 + srow) * K + scol;
  const unsigned short* bg1 = Bt + (size_t)(n0 + 64 + srow) * K + scol;
  const int gsw = (quad ^ (c16 & 3)) * 8;                 // frag-read group
  f32x4 acc[4][4] = {};
  for (int k0 = 0; k0 < K; k0 += 32) {
    async16(ag0 + k0, &As[w * 512]);
    async16(ag1 + k0, &As[w * 512 + 2048]);
    async16(bg0 + k0, &Bs[w * 512]);
    async16(bg1 + k0, &Bs[w * 512 + 2048]);
    __syncthreads();
    bf16x8 af[4], bfr[4];
    #pragma unroll
    for (int mi = 0; mi < 4; ++mi)
      af[mi] = *(const bf16x8*)&As[(wm + mi * 16 + c16) * 32 + gsw];
    #pragma unroll
    for (int ni = 0; ni < 4; ++ni)
      bfr[ni] = *(const bf16x8*)&Bs[(wn + ni * 16 + c16) * 32 + gsw];
    #pragma unroll
    for (int mi = 0; mi < 4; ++mi)
      #pragma unroll
      for (int ni = 0; ni < 4; ++ni)
        acc[mi][ni] = __builtin_amdgcn_mfma_f32_16x16x32_bf16(
            af[mi], bfr[ni], acc[mi][ni], 0, 0, 0);
    __syncthreads();
  }
  #pragma unroll
  for (int mi = 0; mi < 4; ++mi) {
    const int rbase = m0 + wm + mi * 16 + quad * 4;
    const int bidx = rbase >> 11;
    const int t0 = rbase & 2047;
    #pragma unroll
    for (int ni = 0; ni < 4; ++ni) {
      const int colC = n0 + wn + ni * 16 + c16;
      if (colC < 2048) {
        #pragma unroll
        for (int r = 0; r < 4; ++r)
          qkb[(size_t)(rbase + r) * 2048 + colC] = f2b(acc[mi][ni][r]);
      } else {
        const int d = colC - 2048;
        const int hh = d >> 6, dd = d & 63;
        ushort4 pk;
        pk.x = f2b(acc[mi][ni][0]); pk.y = f2b(acc[mi][ni][1]);
        pk.z = f2b(acc[mi][ni][2]); pk.w = f2b(acc[mi][ni][3]);
        *(ushort4*)(vtb + (size_t)((bidx * 16 + hh) * 64 + dd) * 2048 + t0) = pk;
      }
    }
  }
}

// -------- proj GEMM: 128x64 tiles, BK=64, XOR swizzle (R8/R9 form) ---------
__global__ __launch_bounds__(256) void gemm_proj(
    const unsigned short* __restrict__ A, const unsigned short* __restrict__ Bt,
    float* __restrict__ C, int M, int N, int K) {
  __shared__ unsigned short As[128 * 64];
  __shared__ unsigned short Bs[64 * 64];
  const int tid = threadIdx.x;
  const int w = tid >> 6, lane = tid & 63;
  const int quad = lane >> 4, c16 = lane & 15;
  const int c7 = c16 & 7;
  const int m0 = blockIdx.y * 128, n0 = blockIdx.x * 64;
  const int wm = (w & 1) * 64, wn = (w >> 1) * 32;
  const int lrow = lane >> 3;
  const int cg = (lane & 7) ^ lrow;
  const unsigned short* ag = A + (size_t)(m0 + w * 32 + lrow) * K + cg * 8;
  const unsigned short* bg = Bt + (size_t)(n0 + w * 16 + lrow) * K + cg * 8;
  f32x4 acc[4][2] = {};
  for (int k0 = 0; k0 < K; k0 += 64) {
    #pragma unroll
    for (int rnd = 0; rnd < 4; ++rnd)
      async16(ag + (size_t)rnd * 8 * K + k0, &As[(w * 32 + rnd * 8) * 64]);
    #pragma unroll
    for (int rnd = 0; rnd < 2; ++rnd)
      async16(bg + (size_t)rnd * 8 * K + k0, &Bs[(w * 16 + rnd * 8) * 64]);
    __syncthreads();
    #pragma unroll
    for (int ks = 0; ks < 2; ++ks) {
      const int gsw = ((ks * 4 + quad) ^ c7) * 8;
      bf16x8 af[4], bfr[2];
      #pragma unroll
      for (int mi = 0; mi < 4; ++mi)
        af[mi] = *(const bf16x8*)&As[(wm + mi * 16 + c16) * 64 + gsw];
      #pragma unroll
      for (int ni = 0; ni < 2; ++ni)
        bfr[ni] = *(const bf16x8*)&Bs[(wn + ni * 16 + c16) * 64 + gsw];
      #pragma unroll
      for (int mi = 0; mi < 4; ++mi)
        #pragma unroll
        for (int ni = 0; ni < 2; ++ni)
          acc[mi][ni] = __builtin_amdgcn_mfma_f32_16x16x32_bf16(
              af[mi], bfr[ni], acc[mi][ni], 0, 0, 0);
    }
    __syncthreads();
  }
  #pragma unroll
  for (int mi = 0; mi < 4; ++mi)
    #pragma unroll
    for (int ni = 0; ni < 2; ++ni) {
      const int colC = n0 + wn + ni * 16 + c16;
      const int rbase = m0 + wm + mi * 16 + quad * 4;
      #pragma unroll
      for (int r = 0; r < 4; ++r)
        C[(size_t)(rbase + r) * N + colC] = acc[mi][ni][r];
    }
}

// -------- flash attention, S^T form, 32 q/wave (R7/R9/R11-verified) --------
__global__ __launch_bounds__(256) void attn_flash(
    const unsigned short* __restrict__ qk,   // [4096][2048]
    const unsigned short* __restrict__ vtg,  // [(b*16+h)*64+d][2048]
    unsigned short* __restrict__ y) {        // [4096][1024]
  __shared__ unsigned short Ks[2][64 * 64];
  __shared__ unsigned short Vs[2][64 * 64];
  __shared__ unsigned short Pt[128 * 72];    // [q][key]
  const int tid = threadIdx.x;
  const int w = tid >> 6, lane = tid & 63;
  const int quad = lane >> 4, c16 = lane & 15;
  const int c7 = c16 & 7;
  const int b = blockIdx.y >> 4, h = blockIdx.y & 15;
  const int i0 = blockIdx.x * 128;
  const int q0 = i0 + w * 32;

  bf16x8 qb[2][2];
  {
    const size_t qr0 = (size_t)(b * 2048 + q0 + c16) * 2048 + h * 64;
    const size_t qr1 = (size_t)(b * 2048 + q0 + 16 + c16) * 2048 + h * 64;
    qb[0][0] = *(const bf16x8*)(qk + qr0 + quad * 8);
    qb[0][1] = *(const bf16x8*)(qk + qr0 + 32 + quad * 8);
    qb[1][0] = *(const bf16x8*)(qk + qr1 + quad * 8);
    qb[1][1] = *(const bf16x8*)(qk + qr1 + 32 + quad * 8);
  }

  const int lrow = lane >> 3;
  const int cg = (lane & 7) ^ lrow;
  const int row0 = w * 16 + lrow;
  const int t_start = (i0 >= 512) ? ((i0 - 511) >> 6) : 0;
  const int t_end = (i0 + 127) >> 6;

  const unsigned short* kp0 =
      qk + (size_t)(b * 2048 + t_start * 64 + row0) * 2048 + 1024 + h * 64 + cg * 8;
  const unsigned short* kp1 = kp0 + (size_t)8 * 2048;
  const unsigned short* vp0 =
      vtg + (size_t)((b * 16 + h) * 64 + row0) * 2048 + t_start * 64 + cg * 8;
  const unsigned short* vp1 = vp0 + (size_t)8 * 2048;

  async16(kp0, &Ks[0][(w * 16) * 64]);
  async16(kp1, &Ks[0][(w * 16 + 8) * 64]);
  async16(vp0, &Vs[0][(w * 16) * 64]);
  async16(vp1, &Vs[0][(w * 16 + 8) * 64]);
  kp0 += 131072; kp1 += 131072; vp0 += 64; vp1 += 64;
  __syncthreads();

  f32x4 o[4][2] = {};
  float lsum[2] = {0.f, 0.f};
  int cur = 0;

  for (int t = t_start; t <= t_end; ++t) {
    if (t < t_end) {
      unsigned short* kb = &Ks[cur ^ 1][0];
      unsigned short* vb = &Vs[cur ^ 1][0];
      async16(kp0, kb + (w * 16) * 64);
      async16(kp1, kb + (w * 16 + 8) * 64);
      async16(vp0, vb + (w * 16) * 64);
      async16(vp1, vb + (w * 16 + 8) * 64);
      kp0 += 131072; kp1 += 131072; vp0 += 64; vp1 += 64;
    }
    const int kbase = t * 64;
    if (kbase <= q0 + 31 && kbase + 63 >= q0 - 511) {
      const unsigned short* Kc = &Ks[cur][0];
      const unsigned short* Vc = &Vs[cur][0];

      f32x4 s[4][2] = {};
      #pragma unroll
      for (int nb = 0; nb < 4; ++nb) {
        const int row = nb * 16 + c16;
        bf16x8 a0 = *(const bf16x8*)&Kc[row * 64 + (quad ^ c7) * 8];
        bf16x8 a1 = *(const bf16x8*)&Kc[row * 64 + ((quad + 4) ^ c7) * 8];
        #pragma unroll
        for (int n2 = 0; n2 < 2; ++n2) {
          s[nb][n2] = __builtin_amdgcn_mfma_f32_16x16x32_bf16(
              a0, qb[n2][0], s[nb][n2], 0, 0, 0);
          s[nb][n2] = __builtin_amdgcn_mfma_f32_16x16x32_bf16(
              a1, qb[n2][1], s[nb][n2], 0, 0, 0);
        }
      }

      const bool full = (kbase + 63 <= q0) && (kbase >= q0 - 480);
      #pragma unroll
      for (int n2 = 0; n2 < 2; ++n2) {
        const int iq = q0 + n2 * 16 + c16;
        #pragma unroll
        for (int nb = 0; nb < 4; ++nb) {
          ushort4 pk;
          unsigned short* pks = (unsigned short*)&pk;
          #pragma unroll
          for (int r = 0; r < 4; ++r) {
            float sv = s[nb][n2][r] * 0.125f;
            if (!full) {
              const int j = kbase + nb * 16 + quad * 4 + r;
              const bool valid = (j <= iq) && (j >= iq - 511);
              sv = valid ? sv : -3.0e38f;
            }
            const unsigned int pu = __float_as_uint(__expf(sv)) & 0xffff0000u;
            lsum[n2] += __uint_as_float(pu);
            pks[r] = (unsigned short)(pu >> 16);
          }
          *(ushort4*)&Pt[(w * 32 + n2 * 16 + c16) * 72 + nb * 16 + quad * 4] = pk;
        }
      }

      #pragma unroll
      for (int ks2 = 0; ks2 < 2; ++ks2) {
        bf16x8 pb0 = *(const bf16x8*)&Pt[(w * 32 + c16) * 72 + ks2 * 32 + quad * 8];
        bf16x8 pb1 = *(const bf16x8*)&Pt[(w * 32 + 16 + c16) * 72 + ks2 * 32 + quad * 8];
        #pragma unroll
        for (int nb = 0; nb < 4; ++nb) {
          const int row = nb * 16 + c16;
          bf16x8 va = *(const bf16x8*)&Vc[row * 64 + ((quad + 4 * ks2) ^ c7) * 8];
          o[nb][0] = __builtin_amdgcn_mfma_f32_16x16x32_bf16(va, pb0, o[nb][0], 0, 0, 0);
          o[nb][1] = __builtin_amdgcn_mfma_f32_16x16x32_bf16(va, pb1, o[nb][1], 0, 0, 0);
        }
      }
    }
    __syncthreads();
    cur ^= 1;
  }

  #pragma unroll
  for (int n2 = 0; n2 < 2; ++n2) {
    float rs = lsum[n2];
    rs += __shfl_xor(rs, 16);
    rs += __shfl_xor(rs, 32);
    const float inv = 1.0f / rs;
    const int iq = q0 + n2 * 16 + c16;
    #pragma unroll
    for (int nb = 0; nb < 4; ++nb) {
      ushort4 pk;
      unsigned short* pks = (unsigned short*)&pk;
      #pragma unroll
      for (int r = 0; r < 4; ++r) pks[r] = f2b(o[nb][n2][r] * inv);
      *(ushort4*)(y + (size_t)(b * 2048 + iq) * 1024 + h * 64 + nb * 16 + quad * 4) = pk;
    }
  }
}

// ---------------------------------------------------------------------------
extern "C" void kernel_launch(void* const* d_in, const int* in_sizes, int n_in,
                              void* d_out, int out_size, void* d_ws, size_t ws_size,
                              hipStream_t stream) {
  const float* x      = (const float*)d_in[0];  // [4096,1024] fp32
  const float* w_attn = (const float*)d_in[1];  // [1024,3072] fp32
  const float* w_proj = (const float*)d_in[2];  // [1024,1024] fp32
  float* out = (float*)d_out;                   // [4096,1024] fp32

  // ws (bf16 elems): qkb 8M | vtb 4M | wT 3M | pT 1M | xb/y 4M  = 40MB
  unsigned short* qkb = (unsigned short*)d_ws;        // [4096][2048]
  unsigned short* vtb = qkb + (size_t)4096 * 2048;    // [2048][2048]
  unsigned short* wT  = vtb + (size_t)2048 * 2048;    // [3072][1024]
  unsigned short* pT  = wT + (size_t)3072 * 1024;     // [1024][1024]
  unsigned short* xb  = pT + (size_t)1024 * 1024;     // [4096][1024]
  unsigned short* y   = xb;                           // reuse (xb dead post-GEMM1)

  prep<<<dim3(96, 32, 3), 256, 0, stream>>>(x, w_attn, w_proj, xb, wT, pT);

  gemm_qkv<<<dim3(24, 32), 256, 0, stream>>>(xb, wT, qkb, vtb);

  attn_flash<<<dim3(16, 32), 256, 0, stream>>>(qkb, vtb, y);

  gemm_proj<<<dim3(1024 / 64, 4096 / 128), 256, 0, stream>>>(
      y, pT, out, 4096, 1024, 1024);
}